// Round 5
// baseline (2139.338 us; speedup 1.0000x reference)
//
#include <hip/hip_runtime.h>
#include <stdint.h>
#include <stddef.h>

// Problem dims
#define Bn   64
#define Tn   512
#define DINn 512
#define Hn   1024
#define OUTn 128

typedef __attribute__((ext_vector_type(4))) float f32x4;
typedef __attribute__((ext_vector_type(8))) short short8;
typedef __attribute__((ext_vector_type(4))) unsigned int u32x4;

__device__ __forceinline__ unsigned short f2bf(float f){
  unsigned int x = __builtin_bit_cast(unsigned int, f);
  x += 0x7fffu + ((x >> 16) & 1u);           // RNE (values bounded, no NaN/inf)
  return (unsigned short)(x >> 16);
}
__device__ __forceinline__ float bf2f(unsigned short u){
  return __builtin_bit_cast(float, (unsigned int)u << 16);
}
__device__ __forceinline__ float tanh_fast(float v){
  float e = __expf(2.0f * v);
  return 1.0f - 2.0f / (e + 1.0f);
}

// ---- pure-L3 primitives: no buffer_inv, no buffer_wbl2, ever ----
__device__ __forceinline__ void st_flag_L3(unsigned int* p, unsigned v){
  asm volatile("global_store_dword %0, %1, off sc0 sc1" :: "v"(p), "v"(v) : "memory");
}
__device__ __forceinline__ void st_bf_L3(unsigned short* p, unsigned short v){
  unsigned int vv = v;
  asm volatile("global_store_short %0, %1, off sc0 sc1" :: "v"(p), "v"(vv) : "memory");
}
__device__ __forceinline__ unsigned umin4(u32x4 a){
  unsigned m0 = a[0] < a[1] ? a[0] : a[1];
  unsigned m1 = a[2] < a[3] ? a[2] : a[3];
  return m0 < m1 ? m0 : m1;
}
// min of 8 flag words in one 32B line (two dwordx4, single vmcnt drain)
__device__ __forceinline__ unsigned ld_line8(const unsigned int* p){
  u32x4 a, b;
  asm volatile("global_load_dwordx4 %0, %2, off sc0 sc1\n\t"
               "global_load_dwordx4 %1, %3, off sc0 sc1\n\t"
               "s_waitcnt vmcnt(0)"
               : "=&v"(a), "=&v"(b) : "v"(p), "v"(p + 4) : "memory");
  unsigned ma = umin4(a), mb = umin4(b);
  return ma < mb ? ma : mb;
}
// Bounded waits (poll L3 line until min >= want). ~33ms budget each; worst case the
// kernel terminates with visibly-wrong output instead of hanging.
__device__ __forceinline__ void wait8(const unsigned int* p, unsigned want){
  if (!want) return;
  for (int i = 0; i < (1 << 17); ++i){
    if (ld_line8(p) >= want) return;
    if (i > 64) __builtin_amdgcn_s_sleep(2);
  }
}
__device__ __forceinline__ void wait8_dual(const unsigned int* p1, unsigned w1,
                                           const unsigned int* p2, unsigned w2){
  if (!w2){ wait8(p1, w1); return; }
  for (int i = 0; i < (1 << 17); ++i){
    u32x4 a, b, c, d;
    asm volatile("global_load_dwordx4 %0, %4, off sc0 sc1\n\t"
                 "global_load_dwordx4 %1, %5, off sc0 sc1\n\t"
                 "global_load_dwordx4 %2, %6, off sc0 sc1\n\t"
                 "global_load_dwordx4 %3, %7, off sc0 sc1\n\t"
                 "s_waitcnt vmcnt(0)"
                 : "=&v"(a), "=&v"(b), "=&v"(c), "=&v"(d)
                 : "v"(p1), "v"(p1 + 4), "v"(p2), "v"(p2 + 4) : "memory");
    unsigned m1 = umin4(a) < umin4(b) ? umin4(a) : umin4(b);
    unsigned m2 = umin4(c) < umin4(d) ? umin4(c) : umin4(d);
    if (m1 >= w1 && m2 >= w2) return;
    if (i > 64) __builtin_amdgcn_s_sleep(2);
  }
}

// Stage 8 rows x 1024 bf16 (16KB) from L3 into LDS laid out as [kk][kh][r] 16B chunks:
// lds[(kk*32 + kh*8 + r)*16B] = h[r][kk*32 + kh*8 .. +8].  LDS writes are tid-linear
// (zero conflicts); the permutation lives in the global source address (64B-coalesced).
__device__ __forceinline__ void stage8(const unsigned short* base, unsigned short* hl, int tid){
  int i0 = tid, i1 = tid + 512;
  const unsigned short* p0 = base + ((i0 & 7) * 1024 + (i0 >> 5) * 32 + ((i0 >> 3) & 3) * 8);
  const unsigned short* p1 = base + ((i1 & 7) * 1024 + (i1 >> 5) * 32 + ((i1 >> 3) & 3) * 8);
  u32x4 v0, v1;
  asm volatile(
    "global_load_dwordx4 %0, %2, off sc0 sc1\n\t"
    "global_load_dwordx4 %1, %3, off sc0 sc1\n\t"
    "s_waitcnt vmcnt(0)"
    : "=&v"(v0), "=&v"(v1) : "v"(p0), "v"(p1) : "memory");
  *(u32x4*)((char*)hl + i0 * 16) = v0;
  *(u32x4*)((char*)hl + i1 * 16) = v1;
}

// MFMA sweep over K=1024. Read addr = kk*512 + kh*128 + lrow*16: for each kk a wave's
// 32 distinct chunks are 512 consecutive bytes -> conflict-free.
__device__ __forceinline__ f32x4 mfma_tile(const char* lbase, const short8* wf, int lrow, int kh){
  f32x4 a0 = {0.f,0.f,0.f,0.f}, a1 = a0, a2 = a0, a3 = a0;
  int rb = kh * 128 + lrow * 16;
#pragma unroll
  for (int kk = 0; kk < 8; ++kk)
    a0 = __builtin_amdgcn_mfma_f32_16x16x32_bf16(*(const short8*)(lbase + kk*512 + rb), wf[kk], a0, 0,0,0);
#pragma unroll
  for (int kk = 8; kk < 16; ++kk)
    a1 = __builtin_amdgcn_mfma_f32_16x16x32_bf16(*(const short8*)(lbase + kk*512 + rb), wf[kk], a1, 0,0,0);
#pragma unroll
  for (int kk = 16; kk < 24; ++kk)
    a2 = __builtin_amdgcn_mfma_f32_16x16x32_bf16(*(const short8*)(lbase + kk*512 + rb), wf[kk], a2, 0,0,0);
#pragma unroll
  for (int kk = 24; kk < 32; ++kk)
    a3 = __builtin_amdgcn_mfma_f32_16x16x32_bf16(*(const short8*)(lbase + kk*512 + rb), wf[kk], a3, 0,0,0);
  return (a0 + a1) + (a2 + a3);
}

// ---------------- elementwise f32 -> bf16 (vectorized x8) ----------------
__global__ void cvt_bf16x8(const float* __restrict__ in, unsigned short* __restrict__ out,
                           long long n8){
  long long i = (long long)blockIdx.x * blockDim.x + threadIdx.x;
  long long stride = (long long)gridDim.x * blockDim.x;
  for (; i < n8; i += stride){
    const float* p = in + i*8;
    float4 a = *(const float4*)p;
    float4 b = *(const float4*)(p+4);
    short8 v;
    v[0]=(short)f2bf(a.x); v[1]=(short)f2bf(a.y); v[2]=(short)f2bf(a.z); v[3]=(short)f2bf(a.w);
    v[4]=(short)f2bf(b.x); v[5]=(short)f2bf(b.y); v[6]=(short)f2bf(b.z); v[7]=(short)f2bf(b.w);
    *(short8*)(out + i*8) = v;
  }
}

__global__ void bias_combine(const float* __restrict__ a, const float* __restrict__ b, float* __restrict__ o,
                             const float* __restrict__ c, const float* __restrict__ d, float* __restrict__ p){
  int i = blockIdx.x * blockDim.x + threadIdx.x;
  if (i < Hn){ o[i] = a[i] + b[i]; p[i] = c[i] + d[i]; }
}

// ---------------- pre0 GEMM: C[t*Bn+b][n] = sum_k x[b*Tn+t][k]*Wih0[n][k] + bias[n] ----------
__launch_bounds__(256, 2)
__global__ void gemm_pre0(const float* __restrict__ Av, const unsigned short* __restrict__ Bm,
                          const float* __restrict__ bias, unsigned short* __restrict__ C,
                          int N, int K)
{
  __shared__ unsigned short lA[128*64];
  __shared__ unsigned short lB[128*64];
  int bn = blockIdx.x, bm = blockIdx.y;
  int m0 = bm*128, n0 = bn*128;
  int tid = threadIdx.x, lane = tid & 63, w = tid >> 6;
  int wm = (w >> 1)*64, wn = (w & 1)*64;
  int cl = lane & 15, kh = lane >> 4;

  f32x4 acc[4][4];
  f32x4 z = {0.f,0.f,0.f,0.f};
#pragma unroll
  for (int i=0;i<4;i++)
#pragma unroll
    for (int j=0;j<4;j++) acc[i][j]=z;

  for (int k0 = 0; k0 < K; k0 += 64){
    __syncthreads();
#pragma unroll
    for (int r = 0; r < 4; ++r){
      int c = r*256 + tid;
      int row = c >> 3, cof = (c & 7)*8;
      const float* ap = Av + (size_t)(m0+row)*K + k0 + cof;
      float4 a = *(const float4*)ap;
      float4 b = *(const float4*)(ap+4);
      short8 v;
      v[0]=(short)f2bf(a.x); v[1]=(short)f2bf(a.y); v[2]=(short)f2bf(a.z); v[3]=(short)f2bf(a.w);
      v[4]=(short)f2bf(b.x); v[5]=(short)f2bf(b.y); v[6]=(short)f2bf(b.z); v[7]=(short)f2bf(b.w);
      *(short8*)&lA[row*64 + cof] = v;
      const unsigned short* bp = Bm + (size_t)(n0+row)*K + k0 + cof;
      *(short8*)&lB[row*64 + cof] = *(const short8*)bp;
    }
    __syncthreads();
#pragma unroll
    for (int kk = 0; kk < 2; ++kk){
      int kb = kk*32 + kh*8;
      short8 af[4], bfr[4];
#pragma unroll
      for (int i=0;i<4;i++) af[i]  = *(const short8*)&lA[(wm + i*16 + cl)*64 + kb];
#pragma unroll
      for (int j=0;j<4;j++) bfr[j] = *(const short8*)&lB[(wn + j*16 + cl)*64 + kb];
#pragma unroll
      for (int i=0;i<4;i++)
#pragma unroll
        for (int j=0;j<4;j++)
          acc[i][j] = __builtin_amdgcn_mfma_f32_16x16x32_bf16(af[i], bfr[j], acc[i][j], 0,0,0);
    }
  }
#pragma unroll
  for (int j=0;j<4;j++){
    int n = n0 + wn + j*16 + cl;
    float bs = bias[n];
#pragma unroll
    for (int i=0;i<4;i++){
      int mr = m0 + wm + i*16 + kh*4;
#pragma unroll
      for (int e=0;e<4;e++){
        int m = mr + e;                       // m = b*Tn + t
        int b = m >> 9, t = m & (Tn-1);
        C[((size_t)t*Bn + b)*N + n] = f2bf(acc[i][j][e] + bs);
      }
    }
  }
}

// ---------------- fused 3-stage pipelined recurrence (pure-L3, per-slot flags) ----------------
// 192 wgs: role = bx>>6 (0: L0 rec, 1: pre1 GEMV, 2: L1 rec); idx = bx&63;
// group g = idx&7 owns batches [8g,8g+8); slot s = idx>>3 owns cols [128s,128s+128).
// Flag lines: FL[role][g] = 8 words (one per slot), value = steps completed (t+1).
__launch_bounds__(512, 2)
__global__ void rnn_fused(const unsigned short* __restrict__ pre0,
                          unsigned short* __restrict__ h1buf,
                          const float* __restrict__ Whh0,
                          const float* __restrict__ Wih1,
                          const float* __restrict__ Whh1,
                          const float* __restrict__ bias1,
                          unsigned short* __restrict__ roll1,
                          unsigned short* __restrict__ roll2,
                          unsigned int* ctrs)
{
  __shared__ unsigned short hl[8192];   // 16KB staged tile, [kk][kh][r] chunk layout
  int bx = blockIdx.x;
  int role = bx >> 6;
  int idx  = bx & 63;
  int g = idx & 7, s = idx >> 3;
  int tid = threadIdx.x, lane = tid & 63, w = tid >> 6;
  int n0 = s*128 + w*16;
  int cl = lane & 15, kh = lane >> 4, lrow = cl & 7;
  int bb = g*8;
  unsigned int* FLA = ctrs +        g*32;   // 128B-spaced lines
  unsigned int* FLB = ctrs + 256 +  g*32;
  unsigned int* FLC = ctrs + 512 +  g*32;
  unsigned int* myflag = (role == 0 ? FLA : role == 1 ? FLB : FLC) + s;

  // Resident weight slice as MFMA B-fragments: lane holds W[n0+cl][kk*32+kh*8+0..7]
  const float* Wmat = (role == 0) ? Whh0 : (role == 1) ? Wih1 : Whh1;
  short8 wf[32];
  {
    const float* wr = Wmat + (size_t)(n0 + cl)*Hn + kh*8;
#pragma unroll
    for (int kk = 0; kk < 32; ++kk){
      float4 a = *(const float4*)(wr + kk*32);
      float4 b = *(const float4*)(wr + kk*32 + 4);
      short8 v;
      v[0]=(short)f2bf(a.x); v[1]=(short)f2bf(a.y); v[2]=(short)f2bf(a.z); v[3]=(short)f2bf(a.w);
      v[4]=(short)f2bf(b.x); v[5]=(short)f2bf(b.y); v[6]=(short)f2bf(b.z); v[7]=(short)f2bf(b.w);
      wf[kk] = v;
    }
  }
  const char* lbase = (const char*)hl;

  if (role == 0){
    // ---- L0: h1(t) = tanh(pre0(t) + Whh0 h1(t-1)) ----
    for (int t = 0; t < Tn; ++t){
      float pv[4] = {0.f,0.f,0.f,0.f};
      if (kh < 2){                       // plain cached loads (pre0 from prior dispatch)
        const unsigned short* pp = pre0 + ((size_t)t*Bn + bb + kh*4)*Hn + n0 + cl;
#pragma unroll
        for (int j=0;j<4;j++) pv[j] = bf2f(pp[(size_t)j*Hn]);
      }
      if (t > 0){
        wait8(FLA, (unsigned)t);                       // all threads poll; no barrier
        stage8(h1buf + ((size_t)(t-1)*Bn + bb)*Hn, hl, tid);
        __syncthreads();                               // tile staged
      }
      f32x4 acc = {0.f,0.f,0.f,0.f};
      if (t > 0) acc = mfma_tile(lbase, wf, lrow, kh);
      if (kh < 2){
        unsigned short* hp = h1buf + ((size_t)t*Bn + bb + kh*4)*Hn + n0 + cl;
#pragma unroll
        for (int j=0;j<4;j++) st_bf_L3(hp + (size_t)j*Hn, f2bf(tanh_fast(acc[j] + pv[j])));
      }
      __syncthreads();                   // drains all waves' stores (vmcnt 0) -> data at L3
      if (tid == 0) st_flag_L3(myflag, (unsigned)(t+1));
    }
  } else if (role == 1){
    // ---- pre1 GEMV: pre1(t) = Wih1 h1(t) + bias1, ring depth 4 ----
    float bs = bias1[n0 + cl];
    for (int t = 0; t < Tn; ++t){
      wait8_dual(FLA, (unsigned)(t+1), FLC, t >= 4 ? (unsigned)(t-3) : 0u);
      stage8(h1buf + ((size_t)t*Bn + bb)*Hn, hl, tid);
      __syncthreads();
      f32x4 acc = mfma_tile(lbase, wf, lrow, kh);
      if (kh < 2){
        unsigned short* op = roll1 + (size_t)((g*4 + (t&3))*8 + kh*4)*Hn + n0 + cl;
#pragma unroll
        for (int j=0;j<4;j++) st_bf_L3(op + (size_t)j*Hn, f2bf(acc[j] + bs));
      }
      __syncthreads();
      if (tid == 0) st_flag_L3(myflag, (unsigned)(t+1));
    }
  } else {
    // ---- L1: h2(t) = tanh(pre1(t) + Whh1 h2(t-1)), ring depth 2 ----
    for (int t = 0; t < Tn; ++t){
      wait8_dual(FLB, (unsigned)(t+1), FLC, (unsigned)t);
      float pv[4] = {0.f,0.f,0.f,0.f};
      if (kh < 2){
        const unsigned short* pp = roll1 + (size_t)((g*4 + (t&3))*8 + kh*4)*Hn + n0 + cl;
        unsigned int u0,u1,u2,u3;
        asm volatile(
          "global_load_ushort %0, %4, off sc0 sc1\n\t"
          "global_load_ushort %1, %5, off sc0 sc1\n\t"
          "global_load_ushort %2, %6, off sc0 sc1\n\t"
          "global_load_ushort %3, %7, off sc0 sc1\n\t"
          "s_waitcnt vmcnt(0)"
          : "=&v"(u0), "=&v"(u1), "=&v"(u2), "=&v"(u3)
          : "v"(pp), "v"(pp + Hn), "v"(pp + 2*Hn), "v"(pp + 3*Hn)
          : "memory");
        pv[0] = bf2f((unsigned short)u0); pv[1] = bf2f((unsigned short)u1);
        pv[2] = bf2f((unsigned short)u2); pv[3] = bf2f((unsigned short)u3);
      }
      if (t > 0)
        stage8(roll2 + (size_t)((g*2 + ((t-1)&1))*8)*Hn, hl, tid);
      __syncthreads();
      f32x4 acc = {0.f,0.f,0.f,0.f};
      if (t > 0) acc = mfma_tile(lbase, wf, lrow, kh);
      if (kh < 2){
        unsigned short* op = roll2 + (size_t)((g*2 + (t&1))*8 + kh*4)*Hn + n0 + cl;
#pragma unroll
        for (int j=0;j<4;j++) st_bf_L3(op + (size_t)j*Hn, f2bf(tanh_fast(acc[j] + pv[j])));
      }
      __syncthreads();
      if (tid == 0) st_flag_L3(myflag, (unsigned)(t+1));
    }
  }
}

// ---------------- FC head: out[b][o] = h2[b][T-1][:] . Wfc[o][:] + bfc[o] ----------------
__global__ void fc_k(const unsigned short* __restrict__ roll2,
                     const float* __restrict__ Wfc, const float* __restrict__ bfc,
                     float* __restrict__ out)
{
  int gw = (blockIdx.x * blockDim.x + threadIdx.x) >> 6;
  int lane = threadIdx.x & 63;
  int b = gw >> 7, o = gw & 127;
  // h2(T-1) lives in ring slot (T-1)&1 == 1
  const unsigned short* hr = roll2 + (size_t)(((b>>3)*2 + 1)*8 + (b&7))*Hn;
  const float* wr = Wfc + (size_t)o*Hn;
  float s = 0.f;
  for (int k = lane; k < Hn; k += 64) s += bf2f(hr[k]) * wr[k];
#pragma unroll
  for (int off = 32; off > 0; off >>= 1) s += __shfl_down(s, off, 64);
  if (lane == 0) out[b*OUTn + o] = s + bfc[o];
}

// ---------------- host ----------------
extern "C" void kernel_launch(void* const* d_in, const int* in_sizes, int n_in,
                              void* d_out, int out_size, void* d_ws, size_t ws_size,
                              hipStream_t stream)
{
  const float* x    = (const float*)d_in[0];
  const float* Wih0 = (const float*)d_in[1];
  const float* Whh0 = (const float*)d_in[2];
  const float* bih0 = (const float*)d_in[3];
  const float* bhh0 = (const float*)d_in[4];
  const float* Wih1 = (const float*)d_in[5];
  const float* Whh1 = (const float*)d_in[6];
  const float* bih1 = (const float*)d_in[7];
  const float* bhh1 = (const float*)d_in[8];
  const float* Wfc  = (const float*)d_in[9];
  const float* bfc  = (const float*)d_in[10];
  float* out = (float*)d_out;

  // workspace layout (bf16 elements)
  unsigned short* bufP  = (unsigned short*)d_ws;                    // pre0 [T][B][H]
  unsigned short* bufH1 = bufP  + (size_t)Bn*Tn*Hn;                 // h1   [T][B][H]
  unsigned short* wih0b = bufH1 + (size_t)Bn*Tn*Hn;                 // 1MiB
  unsigned short* roll1 = wih0b + (size_t)Hn*DINn;                  // [8][4][8][H]
  unsigned short* roll2 = roll1 + (size_t)8*4*8*Hn;                 // [8][2][8][H]
  float* bias0 = (float*)(roll2 + (size_t)8*2*8*Hn);
  float* bias1 = bias0 + Hn;
  unsigned int* ctrs = (unsigned int*)(bias1 + Hn);                 // 1024 uints

  hipMemsetAsync(ctrs, 0, 1024*sizeof(unsigned int), stream);

  cvt_bf16x8<<<256, 256, 0, stream>>>(Wih0, wih0b, (long long)Hn*DINn/8);
  bias_combine<<<4, 256, 0, stream>>>(bih0, bhh0, bias0, bih1, bhh1, bias1);

  // pre0 = x @ Wih0^T + bias0, written as [T][B][H]
  dim3 g1(Hn/128, (Bn*Tn)/128);
  gemm_pre0<<<g1, 256, 0, stream>>>(x, wih0b, bias0, bufP, Hn, DINn);

  // fused L0-rec -> pre1-GEMV -> L1-rec pipeline
  rnn_fused<<<192, 512, 0, stream>>>(bufP, bufH1, Whh0, Wih1, Whh1, bias1,
                                     roll1, roll2, ctrs);

  // FC head from h2(T-1) ring slot
  fc_k<<<2048, 256, 0, stream>>>(roll2, Wfc, bfc, out);
}